// Round 6
// baseline (214.389 us; speedup 1.0000x reference)
//
#include <hip/hip_runtime.h>
#include <hip/hip_bf16.h>

#define BB 512
#define CC 112
#define DD 128
#define HH 8
#define HD 16
#define KK 8

typedef unsigned short u16;
typedef short short8 __attribute__((ext_vector_type(8)));
typedef float f32x4 __attribute__((ext_vector_type(4)));
typedef float f32x16 __attribute__((ext_vector_type(16)));

#define MFMA16(a, b, c) __builtin_amdgcn_mfma_f32_16x16x32_bf16(a, b, c, 0, 0, 0)
#define MFMA32(a, b, c) __builtin_amdgcn_mfma_f32_32x32x16_bf16(a, b, c, 0, 0, 0)

__device__ inline u16 f2bf(float f) {
  union { float f; unsigned u; } v{f};
  unsigned r = (v.u + 0x7FFFu + ((v.u >> 16) & 1u)) >> 16;
  return (u16)r;
}
__device__ inline float bf2f(u16 u) {
  union { unsigned u; float f; } v;
  v.u = ((unsigned)u) << 16;
  return v.f;
}
__device__ inline unsigned pk2(float a, float b) {
  __hip_bfloat162 h = __float22bfloat162_rn(float2{a, b});
  union { __hip_bfloat162 h; unsigned u; } v{h};
  return v.u;
}

// ---------------------------------------------------------------------------
// K0: convert 4x128x128 fp32 weights (wq,wk,wv,wo concatenated view) -> bf16.
// ---------------------------------------------------------------------------
__global__ __launch_bounds__(256) void k_wcvt(
    const float* __restrict__ wq, const float* __restrict__ wk,
    const float* __restrict__ wv, const float* __restrict__ wo,
    u16* __restrict__ w_b) {
  const int i = (blockIdx.x * 256 + threadIdx.x);  // handles 4 floats
  const int sel = i >> 12, off = i & 4095;         // 4096 float4 per matrix
  const float* w = (sel == 0) ? wq : (sel == 1) ? wk : (sel == 2) ? wv : wo;
  const float4 v = ((const float4*)w)[off];
  ((uint2*)w_b)[i] = uint2{pk2(v.x, v.y), pk2(v.z, v.w)};
}

// ---------------------------------------------------------------------------
// K1: fused conv+GELU+BN+residual+QKV. Block=256 (4 waves), 64 token rows.
// Lane conv-computes its own MFMA A-frag elements in registers; B-frags are
// read DIRECTLY FROM GLOBAL bf16 weights (L1-resident, shared by all blocks).
// Zero LDS, zero barriers. q/k head-major [B,H,C,16]; v transposed [B,H,16,C].
// ---------------------------------------------------------------------------
__global__ __launch_bounds__(256) void k_cqkv(
    const float* __restrict__ x, const float* __restrict__ cw,
    const float* __restrict__ cb, const float* __restrict__ bg,
    const float* __restrict__ bb_, const float* __restrict__ bm,
    const float* __restrict__ bv, const u16* __restrict__ w_b,
    const float* __restrict__ bq, const float* __restrict__ bk,
    const float* __restrict__ bvv,
    u16* __restrict__ src_b, u16* __restrict__ qb, u16* __restrict__ kb,
    u16* __restrict__ vtb) {
  const int t = threadIdx.x;
  const int wave = t >> 6, lane = t & 63;
  const int quad = lane >> 4, n = lane & 15;
  const int row_g = blockIdx.x * 64 + wave * 16 + n;  // this lane's token row
  const int ch = row_g % CC;                          // conv channel

  const float4 w0 = *(const float4*)(cw + ch * KK);
  const float4 w1 = *(const float4*)(cw + ch * KK + 4);
  const float cbv = cb[ch];
  const float bscale = bg[ch] * rsqrtf(bv[ch] + 1e-5f);
  const float bmv = bm[ch], bbv = bb_[ch];

  const float* __restrict__ xr = x + (size_t)row_g * DD;
  u16* __restrict__ sbr = src_b + (size_t)row_g * DD;

  short8 A[4];
#pragma unroll
  for (int kf = 0; kf < 4; ++kf) {
    const int c0 = kf * 32 + quad * 8;  // 8 outputs c0..c0+7
    float in[16];                       // cols c0-4 .. c0+11
#pragma unroll
    for (int f = 0; f < 4; ++f) {
      const int fi = (c0 >> 2) - 1 + f;
      float4 vv = {0.f, 0.f, 0.f, 0.f};
      if (fi >= 0 && fi < 32) vv = ((const float4*)xr)[fi];
      in[f * 4 + 0] = vv.x; in[f * 4 + 1] = vv.y;
      in[f * 4 + 2] = vv.z; in[f * 4 + 3] = vv.w;
    }
    u16 ob[8];
#pragma unroll
    for (int i = 0; i < 8; ++i) {
      float a = 0.f;
      a = fmaf(in[i + 1], w0.x, a);
      a = fmaf(in[i + 2], w0.y, a);
      a = fmaf(in[i + 3], w0.z, a);
      a = fmaf(in[i + 4], w0.w, a);
      a = fmaf(in[i + 5], w1.x, a);
      a = fmaf(in[i + 6], w1.y, a);
      a = fmaf(in[i + 7], w1.z, a);
      a = fmaf(in[i + 8], w1.w, a);
      a += cbv;
      const float g = 0.5f * a * (1.f + erff(a * 0.70710678118654752440f));
      const float s = in[i + 4] + (g - bmv) * bscale + bbv;  // x + BN(GELU)
      ob[i] = f2bf(s);
    }
    A[kf] = *(short8*)ob;
    *(short8*)(sbr + c0) = A[kf];  // bf16 residual for k_out
  }

  // hoisted store bases for MFMA C-layout rows (token = row0w+quad*4+r)
  const int row0w = blockIdx.x * 64 + wave * 16;
  int qk_base[4], vt_base[4];
#pragma unroll
  for (int r = 0; r < 4; ++r) {
    const int g = row0w + quad * 4 + r;
    const int b_ = g / CC, c_ = g - b_ * CC;
    qk_base[r] = (b_ * (HH * CC) + c_) * HD + n;     // + h*CC*HD per head
    vt_base[r] = b_ * (HH * HD * CC) + n * CC + c_;  // + h*HD*CC per head
  }

  const float* const biases[3] = {bq, bk, bvv};
  for (int m = 0; m < 3; ++m) {
    const u16* __restrict__ wm = w_b + m * 16384;
    const float* __restrict__ bias = biases[m];
#pragma unroll
    for (int nt = 0; nt < 8; ++nt) {  // nt == head index
      f32x4 acc = {0.f, 0.f, 0.f, 0.f};
#pragma unroll
      for (int kf = 0; kf < 4; ++kf) {
        const short8 Bf =
            *(const short8*)(wm + (nt * 16 + n) * DD + kf * 32 + quad * 8);
        acc = MFMA16(A[kf], Bf, acc);
      }
      const float bcol = bias[nt * 16 + n];
      if (m < 2) {
        u16* __restrict__ o = (m == 0) ? qb : kb;
        const int hoff = nt * (CC * HD);
#pragma unroll
        for (int r = 0; r < 4; ++r)
          o[qk_base[r] + hoff] = f2bf(acc[r] + bcol);
      } else {
        const int hoff = nt * (HD * CC);
#pragma unroll
        for (int r = 0; r < 4; ++r)
          vtb[vt_base[r] + hoff] = f2bf(acc[r] + bcol);
      }
    }
  }
}

// ---------------------------------------------------------------------------
// K2: attention, block=256 (4 waves) per (b,h); wave owns 32 queries via
// mfma_32x32x16. Scores transposed (S^T = K*Q^T) -> softmax reg-local + one
// shfl_xor(32). PV A-frags built IN REGISTERS: lane(query=lo,hi) needs rows
// R0..R0+3 (hi'=0 lanes) and R0+4..R0+7 (hi'=1 lanes) of P-tile kt>>1 at reg
// quad 2*(kt&1)+hi -- one shfl_xor(32) exchange, no LDS round trip.
// V^T frags read directly from global (read-once). ZERO LDS, ZERO barriers.
// ---------------------------------------------------------------------------
__global__ __launch_bounds__(256) void k_attn(
    const u16* __restrict__ qb_, const u16* __restrict__ kb_,
    const u16* __restrict__ vtb_, u16* __restrict__ ab_) {
  const int bh = blockIdx.x;  // b*HH + h
  const int b = bh >> 3, h = bh & 7;
  const int t = threadIdx.x;
  const int wave = t >> 6;  // query tile (32 queries)
  const int lane = t & 63;
  const int lo = lane & 31;
  const int hi = lane >> 5;
  const int hi8 = hi * 8;
  const u16* __restrict__ qh = qb_ + (size_t)bh * (CC * HD);
  const u16* __restrict__ kh = kb_ + (size_t)bh * (CC * HD);
  const u16* __restrict__ vth = vtb_ + (size_t)bh * (HD * CC);
  u16* __restrict__ aout = ab_ + (size_t)b * (CC * DD) + h * HD;

  const int qt0 = wave * 32;
  short8 Bq = {};
  if (qt0 + lo < CC) Bq = *(const short8*)(qh + (qt0 + lo) * HD + hi8);
  f32x16 sa[4];
#pragma unroll
  for (int mt = 0; mt < 4; ++mt) {
    short8 Ak = {};
    const int key = mt * 32 + lo;
    if (key < CC) Ak = *(const short8*)(kh + key * HD + hi8);
    f32x16 z = {};
    sa[mt] = MFMA32(Ak, Bq, z);
  }
  // lane holds S^T[key = 32*mt + (r&3)+8*(r>>2)+4*hi][query = qt0+lo];
  // valid: mt<3 all regs, mt=3 regs 0..7 (keys 96..111).
  const float C1 = 0.25f * 1.44269504088896341f;  // SCALE * log2(e)
  float mx = -1e30f;
#pragma unroll
  for (int mt = 0; mt < 4; ++mt) {
    const int rmax = (mt == 3) ? 8 : 16;
#pragma unroll
    for (int r = 0; r < 16; ++r)
      if (r < rmax) mx = fmaxf(mx, sa[mt][r]);
  }
  mx = fmaxf(mx, __shfl_xor(mx, 32));
  const float mxc = mx * C1;
  float sum = 0.f;
#pragma unroll
  for (int mt = 0; mt < 4; ++mt) {
    const int rmax = (mt == 3) ? 8 : 16;
#pragma unroll
    for (int r = 0; r < 16; ++r)
      if (r < rmax) {
        const float p = exp2f(fmaf(sa[mt][r], C1, -mxc));
        sa[mt][r] = p;
        sum += p;
      }
  }
  sum += __shfl_xor(sum, 32);
  const float rinv = 1.f / sum;
  // pack normalized P: U0/U1[mt][rq] = bf16x2 pairs of regs 4rq..4rq+3
  unsigned U0[4][4], U1[4][4];
#pragma unroll
  for (int mt = 0; mt < 4; ++mt) {
    const int rqmax = (mt == 3) ? 2 : 4;
#pragma unroll
    for (int rq = 0; rq < 4; ++rq)
      if (rq < rqmax) {
        U0[mt][rq] = pk2(sa[mt][4 * rq + 0] * rinv, sa[mt][4 * rq + 1] * rinv);
        U1[mt][rq] = pk2(sa[mt][4 * rq + 2] * rinv, sa[mt][4 * rq + 3] * rinv);
      }
  }
  // PV: O[32q][16e], 7 K-tiles of 16 keys. A-frag assembled via shfl_xor(32).
  f32x16 oacc = {};
#pragma unroll
  for (int kt = 0; kt < 7; ++kt) {
    const int mt = kt >> 1;
    const int c = 2 * (kt & 1);  // base reg-quad; own = c+hi, sent = c+(1-hi)
    const unsigned own0 = hi ? U0[mt][c + 1] : U0[mt][c];
    const unsigned own1 = hi ? U1[mt][c + 1] : U1[mt][c];
    const unsigned snd0 = hi ? U0[mt][c] : U0[mt][c + 1];
    const unsigned snd1 = hi ? U1[mt][c] : U1[mt][c + 1];
    const unsigned got0 = __shfl_xor(snd0, 32);
    const unsigned got1 = __shfl_xor(snd1, 32);
    union { unsigned u[4]; short8 s; } ap;
    ap.u[0] = hi ? got0 : own0;
    ap.u[1] = hi ? got1 : own1;
    ap.u[2] = hi ? own0 : got0;
    ap.u[3] = hi ? own1 : got1;
    short8 Bv = {};
    if (lo < HD) Bv = *(const short8*)(vth + lo * CC + kt * 16 + hi8);
    oacc = MFMA32(ap.s, Bv, oacc);
  }
  // D[row=query-in-tile][col=e=lo]; store real e / real queries
  if (lo < HD) {
#pragma unroll
    for (int r = 0; r < 16; ++r) {
      const int qrow = qt0 + (r & 3) + 8 * (r >> 2) + 4 * hi;
      if (qrow < CC) aout[(size_t)qrow * DD + lo] = f2bf(oacc[r]);
    }
  }
}

// ---------------------------------------------------------------------------
// K3: out = LN(src + attn @ Wo^T + bo). Wo frags direct from global bf16;
// LN in registers (shfl reduce). Zero LDS, zero barriers.
// ---------------------------------------------------------------------------
__global__ __launch_bounds__(256) void k_out(
    const u16* __restrict__ a_b, const u16* __restrict__ w_bo,
    const float* __restrict__ bo, const u16* __restrict__ src_b,
    const float* __restrict__ lg, const float* __restrict__ lb,
    float* __restrict__ out) {
  const int t = threadIdx.x;
  const int wave = t >> 6, lane = t & 63;
  const int quad = lane >> 4, n = lane & 15;
  const int row0 = blockIdx.x * 64 + wave * 16;
  short8 A[4];
  {
    const size_t rbase = (size_t)(row0 + n) * DD;
#pragma unroll
    for (int kf = 0; kf < 4; ++kf)
      A[kf] = *(const short8*)(a_b + rbase + kf * 32 + quad * 8);
  }
  float v[8][4];
#pragma unroll
  for (int nt = 0; nt < 8; ++nt) {
    f32x4 acc = {0.f, 0.f, 0.f, 0.f};
#pragma unroll
    for (int kf = 0; kf < 4; ++kf) {
      const short8 Bf =
          *(const short8*)(w_bo + (nt * 16 + n) * DD + kf * 32 + quad * 8);
      acc = MFMA16(A[kf], Bf, acc);
    }
    const int col = nt * 16 + n;
    const float bcol = bo[col];
#pragma unroll
    for (int r = 0; r < 4; ++r)
      v[nt][r] = acc[r] + bcol +
                 bf2f(src_b[(size_t)(row0 + quad * 4 + r) * DD + col]);
  }
  float sum[4] = {0.f, 0.f, 0.f, 0.f}, sq[4] = {0.f, 0.f, 0.f, 0.f};
#pragma unroll
  for (int nt = 0; nt < 8; ++nt)
#pragma unroll
    for (int r = 0; r < 4; ++r) {
      sum[r] += v[nt][r];
      sq[r] = fmaf(v[nt][r], v[nt][r], sq[r]);
    }
#pragma unroll
  for (int d = 1; d < 16; d <<= 1)
#pragma unroll
    for (int r = 0; r < 4; ++r) {
      sum[r] += __shfl_xor(sum[r], d);
      sq[r] += __shfl_xor(sq[r], d);
    }
  float mu[4], rs[4];
#pragma unroll
  for (int r = 0; r < 4; ++r) {
    mu[r] = sum[r] * (1.f / DD);
    const float var = sq[r] * (1.f / DD) - mu[r] * mu[r];
    rs[r] = rsqrtf(var + 1e-5f);
  }
#pragma unroll
  for (int nt = 0; nt < 8; ++nt) {
    const int col = nt * 16 + n;
    const float g = lg[col], be = lb[col];
#pragma unroll
    for (int r = 0; r < 4; ++r)
      out[(size_t)(row0 + quad * 4 + r) * DD + col] =
          (v[nt][r] - mu[r]) * rs[r] * g + be;
  }
}

extern "C" void kernel_launch(void* const* d_in, const int* in_sizes, int n_in,
                              void* d_out, int out_size, void* d_ws,
                              size_t ws_size, hipStream_t stream) {
  (void)in_sizes; (void)n_in; (void)out_size; (void)ws_size;
  const float* x   = (const float*)d_in[0];
  const float* cw  = (const float*)d_in[1];
  const float* cb  = (const float*)d_in[2];
  const float* bg  = (const float*)d_in[3];
  const float* bb  = (const float*)d_in[4];
  const float* bm  = (const float*)d_in[5];
  const float* bv  = (const float*)d_in[6];
  const float* wq  = (const float*)d_in[7];
  const float* bq  = (const float*)d_in[8];
  const float* wk  = (const float*)d_in[9];
  const float* bk  = (const float*)d_in[10];
  const float* wv  = (const float*)d_in[11];
  const float* bvv = (const float*)d_in[12];
  const float* wo  = (const float*)d_in[13];
  const float* bo  = (const float*)d_in[14];
  const float* lg  = (const float*)d_in[15];
  const float* lb  = (const float*)d_in[16];
  float* out = (float*)d_out;

  const size_t NE = (size_t)BB * CC * DD;  // 7,340,032
  u16* ub = (u16*)d_ws;
  u16* src_b = ub;            // bf16 src, row-major [B*C, D]
  u16* q_b   = ub + NE;       // head-major [B,H,C,16]
  u16* k_b   = ub + 2 * NE;   // head-major [B,H,C,16]
  u16* vt_b  = ub + 3 * NE;   // transposed head-major [B,H,16,C]
  u16* a_b   = ub + 4 * NE;   // attention out, row-major [B*C, D]
  u16* w_b   = ub + 5 * NE;   // 4 x 128x128 bf16 weights (q,k,v,o)

  k_wcvt<<<64, 256, 0, stream>>>(wq, wk, wv, wo, w_b);
  k_cqkv<<<(BB * CC) / 64, 256, 0, stream>>>(
      x, cw, cb, bg, bb, bm, bv, w_b, bq, bk, bvv, src_b, q_b, k_b, vt_b);
  k_attn<<<BB * HH, 256, 0, stream>>>(q_b, k_b, vt_b, a_b);
  k_out<<<(BB * CC) / 64, 256, 0, stream>>>(a_b, w_b + 3 * 16384, bo, src_b,
                                            lg, lb, out);
}